// Round 1
// baseline (77.180 us; speedup 1.0000x reference)
//
#include <hip/hip_runtime.h>

// FeatureAttentionLayer: B=32, W=128, K=128, E=256, all fp32.
// ref:
//   xp[b,k,w] = x[b,w,k]
//   L[b,k,e] = sum_w xp[b,k,w]*lin_w[e,w]   (+ lin_b[e] folded in)
//   R[b,k,e] = sum_w xp[b,k,w]*lin_w[e,128+w]
//   e[b,i,j] = sum_e a[e]*LReLU(L[b,i,e]+R[b,j,e]) + bias[i,j]
//            = sum_e (0.2a[e]*s + 0.8a[e]*max(s,0)),  s = L+R
//   att = softmax_j(e);  out[b,w,i] = sigmoid(sum_j att[b,i,j]*x[b,w,j])
//
// ws layout (floats): L @ 0 (1M), R @ 1M (1M), a2 @ 2M (256), a8 @ 2M+256 (256)
// total ~8.4 MB of d_ws.

#define WS_L  0
#define WS_R  1048576
#define WS_A2 2097152
#define WS_A8 2097408

__device__ __forceinline__ void ld4(const float* p, float v[4]) {
    float4 q = *(const float4*)p;
    v[0] = q.x; v[1] = q.y; v[2] = q.z; v[3] = q.w;
}

// K1: L/R projection GEMM. grid (32 b, 8 e-tiles), 256 thr.
// thread: ep = t&7 (4 e's), kp = t>>3 (4 k's). acc 4k x 4e x {L,R}.
// All operands streamed via L1/L2 (x[b]=64KB, lin_w rows; 2-3KB live set per
// w-chunk) -- no LDS, no barriers.
__global__ __launch_bounds__(256) void k_linear(
    const float* __restrict__ x, const float* __restrict__ lin_w,
    const float* __restrict__ lin_b, const float* __restrict__ a,
    float* __restrict__ ws)
{
    const int t = threadIdx.x;
    const int b = blockIdx.x, et = blockIdx.y;

    // fold a -> (0.2a, 0.8a) once (any single block; stream-ordered before K2)
    if (b == 0 && et == 0) {
        float av = a[t];
        ws[WS_A2 + t] = 0.2f * av;
        ws[WS_A8 + t] = 0.8f * av;
    }

    const int ep = t & 7;        // e-position: e = et*32 + ep*4 + ee
    const int kp = t >> 3;       // k-position: k = kp*4 + kk
    float accL[4][4] = {{0.f}};  // [kk][ee]
    float accR[4][4] = {{0.f}};

    const float* xb  = x + b * 16384 + kp * 4;           // x[b][w][kp*4..]
    const float* wle = lin_w + (et * 32 + ep * 4) * 256; // rows e..e+3

    for (int wc = 0; wc < 32; ++wc) {
        float xv[4][4], wlv[4][4], wrv[4][4];
        #pragma unroll
        for (int ww = 0; ww < 4; ++ww)
            ld4(xb + (wc * 4 + ww) * 128, xv[ww]);       // xv[ww][kk]
        #pragma unroll
        for (int ee = 0; ee < 4; ++ee) {
            ld4(wle + ee * 256 + wc * 4, wlv[ee]);       // Wl[e][w..w+3]
            ld4(wle + ee * 256 + 128 + wc * 4, wrv[ee]); // Wr[e][w..w+3]
        }
        #pragma unroll
        for (int ee = 0; ee < 4; ++ee)
            #pragma unroll
            for (int ww = 0; ww < 4; ++ww)
                #pragma unroll
                for (int kk = 0; kk < 4; ++kk) {
                    accL[kk][ee] = fmaf(xv[ww][kk], wlv[ee][ww], accL[kk][ee]);
                    accR[kk][ee] = fmaf(xv[ww][kk], wrv[ee][ww], accR[kk][ee]);
                }
    }

    float lb[4];
    #pragma unroll
    for (int ee = 0; ee < 4; ++ee) lb[ee] = lin_b[et * 32 + ep * 4 + ee];

    #pragma unroll
    for (int kk = 0; kk < 4; ++kk) {
        const int k = kp * 4 + kk;
        const int off = (b * 128 + k) * 256 + et * 32 + ep * 4;
        float4 sL = make_float4(accL[kk][0] + lb[0], accL[kk][1] + lb[1],
                                accL[kk][2] + lb[2], accL[kk][3] + lb[3]);
        float4 sR = make_float4(accR[kk][0], accR[kk][1], accR[kk][2], accR[kk][3]);
        *(float4*)&ws[WS_L + off] = sL;
        *(float4*)&ws[WS_R + off] = sR;
    }
}

// K2: fused e-logits + softmax + PV + sigmoid + output transpose.
// grid (32 b, 8 i-tiles of 16 rows), 256 thr.
// phase1 thread: ip = t>>5 (2 i's), jp = t&31 (4 j's: jp+32*jj).
// phase2 thread: iq = t&7 (2 i's), wp = t>>3 (4 w's: wp+32*ww).
// Only LDS use: 16x132 att tile for the phase1->phase2 remap.
__global__ __launch_bounds__(256) void k_attn(
    const float* __restrict__ x, const float* __restrict__ bias,
    const float* __restrict__ ws, float* __restrict__ out)
{
    __shared__ float att[16 * 132];   // stride 132 spreads banks; 8.4 KB

    const int t = threadIdx.x;
    const int b = blockIdx.x, it = blockIdx.y;

    const int jp = t & 31, ip = t >> 5;
    const float* Lg  = ws + WS_L + (size_t)(b * 128 + it * 16 + ip * 2) * 256;
    const float* Rg  = ws + WS_R + (size_t)b * 32768 + jp * 256;
    const float* a2g = ws + WS_A2;
    const float* a8g = ws + WS_A8;

    float acc1[2][4] = {{0.f}};   // sum 0.2a*s   [ii][jj]
    float acc2[2][4] = {{0.f}};   // sum 0.8a*max(s,0)

    for (int ec = 0; ec < 64; ++ec) {
        float lv[2][4], rv[4][4], v2[4], v8[4];
        ld4(a2g + ec * 4, v2);
        ld4(a8g + ec * 4, v8);
        ld4(Lg + ec * 4, lv[0]);
        ld4(Lg + 256 + ec * 4, lv[1]);
        #pragma unroll
        for (int jj = 0; jj < 4; ++jj)
            ld4(Rg + jj * (32 * 256) + ec * 4, rv[jj]);
        #pragma unroll
        for (int u = 0; u < 4; ++u)
            #pragma unroll
            for (int ii = 0; ii < 2; ++ii)
                #pragma unroll
                for (int jj = 0; jj < 4; ++jj) {
                    float s = lv[ii][u] + rv[jj][u];
                    float m = fmaxf(s, 0.f);
                    acc1[ii][jj] = fmaf(v2[u], s, acc1[ii][jj]);
                    acc2[ii][jj] = fmaf(v8[u], m, acc2[ii][jj]);
                }
    }

    // bias + row softmax. Row (ip,ii) lives in one 32-lane half-wave (jp 0..31),
    // so xor-shuffles with mask<=16 stay in-row.
    const int i0 = it * 16 + ip * 2;
    #pragma unroll
    for (int ii = 0; ii < 2; ++ii) {
        float ev[4];
        #pragma unroll
        for (int jj = 0; jj < 4; ++jj)
            ev[jj] = acc1[ii][jj] + acc2[ii][jj]
                   + bias[(i0 + ii) * 128 + jp + 32 * jj];
        float m = fmaxf(fmaxf(ev[0], ev[1]), fmaxf(ev[2], ev[3]));
        #pragma unroll
        for (int d = 1; d <= 16; d <<= 1) m = fmaxf(m, __shfl_xor(m, d));
        float p[4], s = 0.f;
        #pragma unroll
        for (int jj = 0; jj < 4; ++jj) { p[jj] = __expf(ev[jj] - m); s += p[jj]; }
        #pragma unroll
        for (int d = 1; d <= 16; d <<= 1) s += __shfl_xor(s, d);
        const float inv = 1.f / s;
        #pragma unroll
        for (int jj = 0; jj < 4; ++jj)
            att[(ip * 2 + ii) * 132 + jp + 32 * jj] = p[jj] * inv;
    }
    __syncthreads();

    // phase 2: out[b,w,i] = sigmoid(sum_j att[i,j] * x[b,w,j])
    const int wp = t >> 3, iq = t & 7;
    float o[2][4] = {{0.f}};   // [ii][ww]
    const float* xb = x + b * 16384;
    for (int jc = 0; jc < 32; ++jc) {
        float av[2][4], xv[4][4];
        #pragma unroll
        for (int ii = 0; ii < 2; ++ii)
            ld4(&att[(iq * 2 + ii) * 132 + jc * 4], av[ii]);
        #pragma unroll
        for (int ww = 0; ww < 4; ++ww)
            ld4(xb + (wp + 32 * ww) * 128 + jc * 4, xv[ww]);
        #pragma unroll
        for (int u = 0; u < 4; ++u)
            #pragma unroll
            for (int ii = 0; ii < 2; ++ii)
                #pragma unroll
                for (int ww = 0; ww < 4; ++ww)
                    o[ii][ww] = fmaf(av[ii][u], xv[ww][u], o[ii][ww]);
    }
    #pragma unroll
    for (int ii = 0; ii < 2; ++ii)
        #pragma unroll
        for (int ww = 0; ww < 4; ++ww) {
            float z = o[ii][ww];
            out[(size_t)b * 16384 + (wp + 32 * ww) * 128 + it * 16 + iq * 2 + ii]
                = 1.f / (1.f + __expf(-z));
        }
}

extern "C" void kernel_launch(void* const* d_in, const int* in_sizes, int n_in,
                              void* d_out, int out_size, void* d_ws, size_t ws_size,
                              hipStream_t stream) {
    const float* x     = (const float*)d_in[0];
    const float* lin_w = (const float*)d_in[1];
    const float* lin_b = (const float*)d_in[2];
    const float* a     = (const float*)d_in[3];
    const float* bias  = (const float*)d_in[4];
    float* ws  = (float*)d_ws;
    float* out = (float*)d_out;

    k_linear<<<dim3(32, 8), 256, 0, stream>>>(x, lin_w, lin_b, a, ws);
    k_attn  <<<dim3(32, 8), 256, 0, stream>>>(x, bias, ws, out);
}